// Round 10
// baseline (79.114 us; speedup 1.0000x reference)
//
#include <hip/hip_runtime.h>
#include <hip/hip_bf16.h>
#include <math.h>

#define D 8192
#define NT 256

// ---------- wave (64-lane) shuffle reductions ----------
__device__ __forceinline__ float wave_sum(float v) {
    #pragma unroll
    for (int o = 32; o > 0; o >>= 1) v += __shfl_xor(v, o, 64);
    return v;
}

// ======== K1a: quarter-row top-8 candidates (512 rows x 4 chunks = 2048 blocks) ========
__global__ __launch_bounds__(NT) void k_topk4(
    const float* __restrict__ teacher, const float* __restrict__ center,
    float* __restrict__ cand_v, int* __restrict__ cand_i, float* __restrict__ out)
{
    const int bid = blockIdx.x;
    const int row = bid >> 2;       // 0..511
    const int ch  = bid & 3;        // 0..3 (2048 cols each)
    const int t = threadIdx.x;
    const int lane = t & 63, w = t >> 6;
    __shared__ float svv[8][4];
    __shared__ int   sii[8][4];

    if (bid == 0 && t == 0) out[0] = 0.f;   // zero loss accumulator (before k_main)

    // 8 elems/thread: cols ch*2048 + t*4 + {0..3} and ch*2048 + 1024 + t*4 + {0..3}
    const float* trow = teacher + (size_t)row * D + ch * 2048;
    const float* crow = center + ch * 2048;
    float z[8];
    {
        float4 tv0 = *(const float4*)(trow + t * 4);
        float4 cv0 = *(const float4*)(crow + t * 4);
        float4 tv1 = *(const float4*)(trow + 1024 + t * 4);
        float4 cv1 = *(const float4*)(crow + 1024 + t * 4);
        z[0] = tv0.x - cv0.x; z[1] = tv0.y - cv0.y; z[2] = tv0.z - cv0.z; z[3] = tv0.w - cv0.w;
        z[4] = tv1.x - cv1.x; z[5] = tv1.y - cv1.y; z[6] = tv1.z - cv1.z; z[7] = tv1.w - cv1.w;
    }

    // thread-local argmax cache (code = (t<<3)|j); only popped owner rescans
    float mvl = -INFINITY; int mjl = 0;
    #pragma unroll
    for (int j = 0; j < 8; ++j)
        if (z[j] > mvl) { mvl = z[j]; mjl = j; }

    float topv[8]; int topc[8];
    #pragma unroll 1
    for (int k = 0; k < 8; ++k) {
        float mv = mvl;
        int mc = (t << 3) | mjl;
        #pragma unroll
        for (int o = 32; o > 0; o >>= 1) {
            float ov = __shfl_xor(mv, o, 64);
            int   oc = __shfl_xor(mc, o, 64);
            if (ov > mv) { mv = ov; mc = oc; }
        }
        if (lane == 0) { svv[k][w] = mv; sii[k][w] = mc; }
        __syncthreads();
        float gv = svv[k][0]; int gc = sii[k][0];
        #pragma unroll
        for (int j = 1; j < 4; ++j)
            if (svv[k][j] > gv) { gv = svv[k][j]; gc = sii[k][j]; }
        topv[k] = gv; topc[k] = gc;
        if ((gc >> 3) == t) {
            z[gc & 7] = -INFINITY;
            mvl = -INFINITY; mjl = 0;
            #pragma unroll
            for (int j = 0; j < 8; ++j)
                if (z[j] > mvl) { mvl = z[j]; mjl = j; }
        }
    }

    if (t == 0) {
        #pragma unroll
        for (int k = 0; k < 8; ++k) {
            const int q = topc[k] >> 3, j = topc[k] & 7;
            const int col = ch * 2048 + ((j < 4) ? (q * 4 + j) : (1024 + q * 4 + (j - 4)));
            cand_v[(size_t)row * 32 + ch * 8 + k] = topv[k];
            cand_i[(size_t)row * 32 + ch * 8 + k] = col;
        }
    }
}

// ======== K1b: merge 32 candidates -> top-8 + weights; one WAVE per row ========
__global__ __launch_bounds__(NT) void k_merge(
    const float* __restrict__ cand_v, const int* __restrict__ cand_i,
    const int* __restrict__ epoch_p,
    int* __restrict__ idx_ws, float* __restrict__ p_ws)
{
    const int t = threadIdx.x;
    const int lane = t & 63, w = t >> 6;
    const int row = blockIdx.x * 4 + w;   // 128 blocks x 4 waves = 512 rows

    float v = (lane < 32) ? cand_v[(size_t)row * 32 + lane] : -INFINITY;
    int   idx = (lane < 32) ? cand_i[(size_t)row * 32 + lane] : 0;
    int payload = (idx << 6) | lane;      // idx<8192 -> fits; low 6 bits = owner lane

    float topv[8]; int topi[8];
    #pragma unroll
    for (int k = 0; k < 8; ++k) {
        float mv = v; int mp = payload;
        #pragma unroll
        for (int o = 32; o > 0; o >>= 1) {
            float ov = __shfl_xor(mv, o, 64);
            int   op = __shfl_xor(mp, o, 64);
            if (ov > mv) { mv = ov; mp = op; }
        }
        topv[k] = mv; topi[k] = mp >> 6;
        if (lane == (mp & 63)) v = -INFINITY;   // pop winner
    }

    if (lane == 0) {
        const int e = epoch_p[0];
        const float temp = (e < 30) ? (0.04f + 0.03f * (float)e / 29.0f) : 0.07f;
        float wgt[8]; float norm = 0.f;
        #pragma unroll
        for (int k = 0; k < 8; ++k) { wgt[k] = __expf((topv[k] - topv[0]) / temp); norm += wgt[k]; }
        const float invn = 1.0f / norm;
        #pragma unroll
        for (int k = 0; k < 8; ++k) {
            p_ws[row * 8 + k] = wgt[k] * invn;
            idx_ws[row * 8 + k] = topi[k];
        }
    }
}

// ========= K2: gather predictor rows (blocks 0..2047) + teacher colsum (2048..2175) =====
__global__ __launch_bounds__(NT) void k_gather_colsum(
    const float* __restrict__ pred, const int* __restrict__ idx_ws,
    const float* __restrict__ p_ws, const float* __restrict__ teacher,
    float* __restrict__ g_ws, float* __restrict__ part_lse, float* __restrict__ part)
{
    const int bid = blockIdx.x;
    const int t = threadIdx.x;

    if (bid >= 2048) {
        // ---- colsum role ----
        const int cb = bid - 2048;
        const int rc = cb >> 3, dc = cb & 7;
        const int d0 = dc * 1024 + t * 4;
        const float* base = teacher + (size_t)rc * 32 * D + d0;
        float4 acc = make_float4(0.f, 0.f, 0.f, 0.f);
        #pragma unroll 4
        for (int r = 0; r < 32; ++r) {
            float4 x = *(const float4*)(base + (size_t)r * D);
            acc.x += x.x; acc.y += x.y; acc.z += x.z; acc.w += x.w;
        }
        *(float4*)(part + (size_t)rc * D + d0) = acc;
        return;
    }

    // ---- gather role ----
    const int row = bid >> 2;          // 0..511
    const int ch  = bid & 3;           // 0..3
    const int lane = t & 63, w = t >> 6;
    const int d0 = ch * 2048 + t * 4;
    __shared__ float sred[4][8];

    int jk[8]; float pk[8];
    #pragma unroll
    for (int k = 0; k < 8; ++k) {
        jk[k] = idx_ws[row * 8 + k];
        pk[k] = p_ws[row * 8 + k];
    }

    float4 a0 = make_float4(0.f,0.f,0.f,0.f), a1 = make_float4(0.f,0.f,0.f,0.f);
    float se[8];
    #pragma unroll
    for (int k = 0; k < 8; ++k) {
        const float* prow = pred + (size_t)jk[k] * D;
        float4 x0 = *(const float4*)(prow + d0);
        float4 x1 = *(const float4*)(prow + d0 + 1024);
        // 10*P bounded (~|1.2|) -> plain sum-exp is exact logsumexp
        se[k] = __expf(x0.x*10.f) + __expf(x0.y*10.f) + __expf(x0.z*10.f) + __expf(x0.w*10.f)
              + __expf(x1.x*10.f) + __expf(x1.y*10.f) + __expf(x1.z*10.f) + __expf(x1.w*10.f);
        const float p = pk[k];
        a0.x += p*x0.x; a0.y += p*x0.y; a0.z += p*x0.z; a0.w += p*x0.w;
        a1.x += p*x1.x; a1.y += p*x1.y; a1.z += p*x1.z; a1.w += p*x1.w;
    }
    float* grow = g_ws + (size_t)row * D;
    *(float4*)(grow + d0)        = a0;
    *(float4*)(grow + d0 + 1024) = a1;

    #pragma unroll
    for (int k = 0; k < 8; ++k) se[k] = wave_sum(se[k]);
    if (lane == 0) {
        #pragma unroll
        for (int k = 0; k < 8; ++k) sred[w][k] = se[k];
    }
    __syncthreads();
    if (t < 8)
        part_lse[(size_t)bid * 8 + t] =
            sred[0][t] + sred[1][t] + sred[2][t] + sred[3][t];
}

// ==== K3: blocks 0,1 = c-term finalize->atomic loss; block 2 = center; 3.. = student ====
__global__ __launch_bounds__(NT) void k_main(
    const float* __restrict__ student, const float* __restrict__ g_ws,
    const float* __restrict__ p_ws, const float* __restrict__ part_lse,
    const float* __restrict__ part, const float* __restrict__ center,
    float* __restrict__ out)
{
    const int bid = blockIdx.x;
    const int t = threadIdx.x;
    const int lane = t & 63, w = t >> 6;

    if (bid < 2) {
        // ---- c-term finalize: r = bid*256 + t; pair multiplicity 7 (iq=0) or 6 (iq=1) ----
        __shared__ float sm4[4];
        const int r = (bid << 8) | t;
        float c = 0.f;
        #pragma unroll
        for (int k = 0; k < 8; ++k) {
            float s = part_lse[(size_t)(r*4+0)*8+k] + part_lse[(size_t)(r*4+1)*8+k]
                    + part_lse[(size_t)(r*4+2)*8+k] + part_lse[(size_t)(r*4+3)*8+k];
            c += p_ws[r * 8 + k] * __logf(s);
        }
        const float wgt = (bid == 0) ? 7.0f : 6.0f;
        float vv = wave_sum(c * wgt * (1.0f / 3328.0f));
        if (lane == 0) sm4[w] = vv;
        __syncthreads();
        if (t == 0) atomicAdd(out, sm4[0] + sm4[1] + sm4[2] + sm4[3]);
        return;
    }

    if (bid == 2) {
        // ---- center: batch_center, EMA, entropies ----
        __shared__ float sm4[4];
        float c[32], bc[32];
        #pragma unroll
        for (int i = 0; i < 8; ++i) {
            const int d = i * 1024 + t * 4;
            float4 cv = *(const float4*)(center + d);
            float4 s = make_float4(0.f, 0.f, 0.f, 0.f);
            for (int rc = 0; rc < 16; ++rc) {
                float4 p = *(const float4*)(part + (size_t)rc * D + d);
                s.x += p.x; s.y += p.y; s.z += p.z; s.w += p.w;
            }
            const float sc = 1.0f / 512.0f;
            bc[i*4+0] = s.x * sc; bc[i*4+1] = s.y * sc;
            bc[i*4+2] = s.z * sc; bc[i*4+3] = s.w * sc;
            c[i*4+0] = cv.x; c[i*4+1] = cv.y; c[i*4+2] = cv.z; c[i*4+3] = cv.w;
            out[3 + d + 0] = cv.x * 0.9f + bc[i*4+0] * 0.1f;
            out[3 + d + 1] = cv.y * 0.9f + bc[i*4+1] * 0.1f;
            out[3 + d + 2] = cv.z * 0.9f + bc[i*4+2] * 0.1f;
            out[3 + d + 3] = cv.w * 0.9f + bc[i*4+3] * 0.1f;
        }

        float mc = -INFINITY, mb = -INFINITY;
        #pragma unroll
        for (int i = 0; i < 32; ++i) { mc = fmaxf(mc, c[i]); mb = fmaxf(mb, bc[i]); }
        #pragma unroll
        for (int o = 32; o > 0; o >>= 1) {
            mc = fmaxf(mc, __shfl_xor(mc, o, 64));
            mb = fmaxf(mb, __shfl_xor(mb, o, 64));
        }
        if (lane == 0) sm4[w] = mc;
        __syncthreads();
        mc = fmaxf(fmaxf(sm4[0], sm4[1]), fmaxf(sm4[2], sm4[3]));
        __syncthreads();
        if (lane == 0) sm4[w] = mb;
        __syncthreads();
        mb = fmaxf(fmaxf(sm4[0], sm4[1]), fmaxf(sm4[2], sm4[3]));
        __syncthreads();

        float zc = 0.f, zb = 0.f;
        #pragma unroll
        for (int i = 0; i < 32; ++i) { zc += __expf(c[i] - mc); zb += __expf(bc[i] - mb); }
        zc = wave_sum(zc); zb = wave_sum(zb);
        if (lane == 0) sm4[w] = zc;
        __syncthreads();
        zc = sm4[0] + sm4[1] + sm4[2] + sm4[3];
        __syncthreads();
        if (lane == 0) sm4[w] = zb;
        __syncthreads();
        zb = sm4[0] + sm4[1] + sm4[2] + sm4[3];
        __syncthreads();
        const float lnZc = __logf(zc);

        float te = 0.f, en = 0.f;
        #pragma unroll
        for (int i = 0; i < 32; ++i) {
            const float lsm = c[i] - mc - lnZc;
            te += __expf(c[i] - mc) * lsm;
            en += __expf(bc[i] - mb) * lsm;
        }
        te = wave_sum(te); en = wave_sum(en);
        if (lane == 0) sm4[w] = te;
        __syncthreads();
        te = sm4[0] + sm4[1] + sm4[2] + sm4[3];
        __syncthreads();
        if (lane == 0) sm4[w] = en;
        __syncthreads();
        en = sm4[0] + sm4[1] + sm4[2] + sm4[3];
        if (t == 0) {
            out[1] = en / zb;
            out[2] = te / zc;
        }
        return;
    }

    // ---- student role: rows 256..2047 ----
    __shared__ float smax[4];
    __shared__ float sred3[4][3];
    const int row = 256 + (bid - 3);
    const int v = row >> 8;             // 1..7
    const int b = row & 255;

    float y[32];
    const float* srow = student + (size_t)row * D;
    float m = -INFINITY;
    #pragma unroll
    for (int i = 0; i < 8; ++i) {
        float4 x = *(const float4*)(srow + i * 1024 + t * 4);
        y[i*4+0] = x.x * 10.f; y[i*4+1] = x.y * 10.f;
        y[i*4+2] = x.z * 10.f; y[i*4+3] = x.w * 10.f;
        m = fmaxf(m, fmaxf(fmaxf(y[i*4+0], y[i*4+1]), fmaxf(y[i*4+2], y[i*4+3])));
    }
    #pragma unroll
    for (int o = 32; o > 0; o >>= 1) m = fmaxf(m, __shfl_xor(m, o, 64));
    if (lane == 0) smax[w] = m;
    __syncthreads();
    const float M = fmaxf(fmaxf(smax[0], smax[1]), fmaxf(smax[2], smax[3]));

    float zs = 0.f;
    #pragma unroll
    for (int i = 0; i < 32; ++i) { y[i] = __expf(y[i] - M); zs += y[i]; }

    const float* g0 = g_ws + (size_t)b * D;
    const float* g1 = g_ws + (size_t)(256 + b) * D;
    float a0 = 0.f, a1 = 0.f;
    #pragma unroll
    for (int i = 0; i < 8; ++i) {
        float4 gg = *(const float4*)(g0 + i * 1024 + t * 4);
        a0 += y[i*4+0]*gg.x + y[i*4+1]*gg.y + y[i*4+2]*gg.z + y[i*4+3]*gg.w;
    }
    if (v >= 2) {
        #pragma unroll
        for (int i = 0; i < 8; ++i) {
            float4 gg = *(const float4*)(g1 + i * 1024 + t * 4);
            a1 += y[i*4+0]*gg.x + y[i*4+1]*gg.y + y[i*4+2]*gg.z + y[i*4+3]*gg.w;
        }
    }
    zs = wave_sum(zs); a0 = wave_sum(a0); a1 = wave_sum(a1);
    if (lane == 0) { sred3[w][0] = zs; sred3[w][1] = a0; sred3[w][2] = a1; }
    __syncthreads();
    if (t == 0) {
        const float Z  = sred3[0][0] + sred3[1][0] + sred3[2][0] + sred3[3][0];
        const float A0 = sred3[0][1] + sred3[1][1] + sred3[2][1] + sred3[3][1];
        const float A1 = sred3[0][2] + sred3[1][2] + sred3[2][2] + sred3[3][2];
        const float invZ = 1.0f / Z;
        float term = -10.f * A0 * invZ;
        if (v >= 2) term += -10.f * A1 * invZ;
        atomicAdd(out, term * (1.0f / 3328.0f));
    }
}

extern "C" void kernel_launch(void* const* d_in, const int* in_sizes, int n_in,
                              void* d_out, int out_size, void* d_ws, size_t ws_size,
                              hipStream_t stream) {
    const float* student = (const float*)d_in[0];
    const float* teacher = (const float*)d_in[1];
    const float* pred    = (const float*)d_in[2];
    const float* center  = (const float*)d_in[3];
    const int*   epoch   = (const int*)d_in[4];
    float* out = (float*)d_out;

    float* g_ws     = (float*)d_ws;                     // 512*8192 f (16 MB)
    float* part     = g_ws + (size_t)512 * D;           // 16*8192 f (512 KB)
    int*   idx_ws   = (int*)(part + (size_t)16 * D);    // 512*8 i
    float* p_ws     = (float*)(idx_ws + 512 * 8);       // 512*8 f
    float* part_lse = p_ws + 512 * 8;                   // 2048*8 f
    float* cand_v   = part_lse + 2048 * 8;              // 512*32 f
    int*   cand_i   = (int*)(cand_v + 512 * 32);        // 512*32 i

    k_topk4<<<2048, NT, 0, stream>>>(teacher, center, cand_v, cand_i, out);
    k_merge<<<128, NT, 0, stream>>>(cand_v, cand_i, epoch, idx_ws, p_ws);
    k_gather_colsum<<<2176, NT, 0, stream>>>(pred, idx_ws, p_ws, teacher,
                                             g_ws, part_lse, part);
    k_main<<<1795, NT, 0, stream>>>(student, g_ws, p_ws, part_lse, part, center, out);
}

// Round 11
// 76.515 us; speedup vs baseline: 1.0340x; 1.0340x over previous
//
#include <hip/hip_runtime.h>
#include <hip/hip_bf16.h>
#include <math.h>

#define D 8192
#define NT 256

// ---------- wave (64-lane) shuffle reductions ----------
__device__ __forceinline__ float wave_sum(float v) {
    #pragma unroll
    for (int o = 32; o > 0; o >>= 1) v += __shfl_xor(v, o, 64);
    return v;
}

// ================= K1: per teacher row: top-8 + weights (also zeroes out[0]) ==========
__global__ __launch_bounds__(NT) void k_topk(
    const float* __restrict__ teacher, const float* __restrict__ center,
    const int* __restrict__ epoch_p,
    int* __restrict__ idx_ws, float* __restrict__ p_ws, float* __restrict__ out)
{
    const int row = blockIdx.x;     // 0..511
    const int t = threadIdx.x;
    const int lane = t & 63, w = t >> 6;
    __shared__ float svv[8][4];
    __shared__ int   sii[8][4];

    if (row == 0 && t == 0) out[0] = 0.f;   // loss accumulator reset (before k_main adds)

    const int e = epoch_p[0];
    const float temp = (e < 30) ? (0.04f + 0.03f * (float)e / 29.0f) : 0.07f;

    // z = teacher - center, 32 elems/thread
    float z[32];
    const float* trow = teacher + (size_t)row * D;
    #pragma unroll
    for (int i = 0; i < 8; ++i) {
        const int d = i * 1024 + t * 4;
        float4 tv = *(const float4*)(trow + d);
        float4 cv = *(const float4*)(center + d);
        z[i*4+0] = tv.x - cv.x; z[i*4+1] = tv.y - cv.y;
        z[i*4+2] = tv.z - cv.z; z[i*4+3] = tv.w - cv.w;
    }

    // cached thread-local argmax; only popped owner rescans
    float mvl = -INFINITY; int mil = 0;
    #pragma unroll
    for (int i = 0; i < 32; ++i)
        if (z[i] > mvl) { mvl = z[i]; mil = i; }

    float topv[8]; int topd[8];
    #pragma unroll 1
    for (int k = 0; k < 8; ++k) {
        float mv = mvl;
        int md = ((mil >> 2) << 10) + t * 4 + (mil & 3);
        #pragma unroll
        for (int o = 32; o > 0; o >>= 1) {
            float ov = __shfl_xor(mv, o, 64);
            int   od = __shfl_xor(md, o, 64);
            if (ov > mv) { mv = ov; md = od; }
        }
        if (lane == 0) { svv[k][w] = mv; sii[k][w] = md; }
        __syncthreads();
        float gv = svv[k][0]; int gd = sii[k][0];
        #pragma unroll
        for (int j = 1; j < 4; ++j)
            if (svv[k][j] > gv) { gv = svv[k][j]; gd = sii[k][j]; }
        topv[k] = gv; topd[k] = gd;
        if (((gd & 1023) >> 2) == t) {
            z[((gd >> 10) << 2) | (gd & 3)] = -INFINITY;
            mvl = -INFINITY; mil = 0;
            #pragma unroll
            for (int i = 0; i < 32; ++i)
                if (z[i] > mvl) { mvl = z[i]; mil = i; }
        }
    }

    if (t == 0) {
        float wgt[8]; float norm = 0.f;
        #pragma unroll
        for (int k = 0; k < 8; ++k) { wgt[k] = __expf((topv[k] - topv[0]) / temp); norm += wgt[k]; }
        const float invn = 1.0f / norm;
        #pragma unroll
        for (int k = 0; k < 8; ++k) {
            p_ws[row * 8 + k] = wgt[k] * invn;
            idx_ws[row * 8 + k] = topd[k];
        }
    }
}

// ========= K2: gather predictor rows (blocks 0..2047) + teacher colsum (2048..2175) =====
__global__ __launch_bounds__(NT) void k_gather_colsum(
    const float* __restrict__ pred, const int* __restrict__ idx_ws,
    const float* __restrict__ p_ws, const float* __restrict__ teacher,
    float* __restrict__ g_ws, float* __restrict__ part_lse, float* __restrict__ part)
{
    const int bid = blockIdx.x;
    const int t = threadIdx.x;

    if (bid >= 2048) {
        // ---- colsum role ----
        const int cb = bid - 2048;
        const int rc = cb >> 3, dc = cb & 7;
        const int d0 = dc * 1024 + t * 4;
        const float* base = teacher + (size_t)rc * 32 * D + d0;
        float4 acc = make_float4(0.f, 0.f, 0.f, 0.f);
        #pragma unroll 4
        for (int r = 0; r < 32; ++r) {
            float4 x = *(const float4*)(base + (size_t)r * D);
            acc.x += x.x; acc.y += x.y; acc.z += x.z; acc.w += x.w;
        }
        *(float4*)(part + (size_t)rc * D + d0) = acc;
        return;
    }

    // ---- gather role ----
    const int row = bid >> 2;          // 0..511
    const int ch  = bid & 3;           // 0..3
    const int lane = t & 63, w = t >> 6;
    const int d0 = ch * 2048 + t * 4;
    __shared__ float sred[4][8];

    int jk[8]; float pk[8];
    #pragma unroll
    for (int k = 0; k < 8; ++k) {
        jk[k] = idx_ws[row * 8 + k];
        pk[k] = p_ws[row * 8 + k];
    }

    float4 a0 = make_float4(0.f,0.f,0.f,0.f), a1 = make_float4(0.f,0.f,0.f,0.f);
    float se[8];
    #pragma unroll
    for (int k = 0; k < 8; ++k) {
        const float* prow = pred + (size_t)jk[k] * D;
        float4 x0 = *(const float4*)(prow + d0);
        float4 x1 = *(const float4*)(prow + d0 + 1024);
        se[k] = __expf(x0.x*10.f) + __expf(x0.y*10.f) + __expf(x0.z*10.f) + __expf(x0.w*10.f)
              + __expf(x1.x*10.f) + __expf(x1.y*10.f) + __expf(x1.z*10.f) + __expf(x1.w*10.f);
        const float p = pk[k];
        a0.x += p*x0.x; a0.y += p*x0.y; a0.z += p*x0.z; a0.w += p*x0.w;
        a1.x += p*x1.x; a1.y += p*x1.y; a1.z += p*x1.z; a1.w += p*x1.w;
    }
    float* grow = g_ws + (size_t)row * D;
    *(float4*)(grow + d0)        = a0;
    *(float4*)(grow + d0 + 1024) = a1;

    #pragma unroll
    for (int k = 0; k < 8; ++k) se[k] = wave_sum(se[k]);
    if (lane == 0) {
        #pragma unroll
        for (int k = 0; k < 8; ++k) sred[w][k] = se[k];
    }
    __syncthreads();
    if (t < 8)
        part_lse[(size_t)bid * 8 + t] =
            sred[0][t] + sred[1][t] + sred[2][t] + sred[3][t];
}

// ==== K3: blocks 0,1 = c-term finalize->atomic loss; block 2 = center; 3.. = student ====
__global__ __launch_bounds__(NT) void k_main(
    const float* __restrict__ student, const float* __restrict__ g_ws,
    const float* __restrict__ p_ws, const float* __restrict__ part_lse,
    const float* __restrict__ part, const float* __restrict__ center,
    float* __restrict__ out)
{
    const int bid = blockIdx.x;
    const int t = threadIdx.x;
    const int lane = t & 63, w = t >> 6;

    if (bid < 2) {
        // ---- c-term finalize: r = bid*256 + t; pair multiplicity 7 (iq=0) or 6 (iq=1) ----
        __shared__ float sm4[4];
        const int r = (bid << 8) | t;
        float c = 0.f;
        #pragma unroll
        for (int k = 0; k < 8; ++k) {
            float s = part_lse[(size_t)(r*4+0)*8+k] + part_lse[(size_t)(r*4+1)*8+k]
                    + part_lse[(size_t)(r*4+2)*8+k] + part_lse[(size_t)(r*4+3)*8+k];
            c += p_ws[r * 8 + k] * __logf(s);
        }
        const float wgt = (bid == 0) ? 7.0f : 6.0f;
        float vv = wave_sum(c * wgt * (1.0f / 3328.0f));
        if (lane == 0) sm4[w] = vv;
        __syncthreads();
        if (t == 0) atomicAdd(out, sm4[0] + sm4[1] + sm4[2] + sm4[3]);
        return;
    }

    if (bid == 2) {
        // ---- center: batch_center, EMA, entropies ----
        __shared__ float sm4[4];
        float c[32], bc[32];
        #pragma unroll
        for (int i = 0; i < 8; ++i) {
            const int d = i * 1024 + t * 4;
            float4 cv = *(const float4*)(center + d);
            float4 s = make_float4(0.f, 0.f, 0.f, 0.f);
            for (int rc = 0; rc < 16; ++rc) {
                float4 p = *(const float4*)(part + (size_t)rc * D + d);
                s.x += p.x; s.y += p.y; s.z += p.z; s.w += p.w;
            }
            const float sc = 1.0f / 512.0f;
            bc[i*4+0] = s.x * sc; bc[i*4+1] = s.y * sc;
            bc[i*4+2] = s.z * sc; bc[i*4+3] = s.w * sc;
            c[i*4+0] = cv.x; c[i*4+1] = cv.y; c[i*4+2] = cv.z; c[i*4+3] = cv.w;
            out[3 + d + 0] = cv.x * 0.9f + bc[i*4+0] * 0.1f;
            out[3 + d + 1] = cv.y * 0.9f + bc[i*4+1] * 0.1f;
            out[3 + d + 2] = cv.z * 0.9f + bc[i*4+2] * 0.1f;
            out[3 + d + 3] = cv.w * 0.9f + bc[i*4+3] * 0.1f;
        }

        float mc = -INFINITY, mb = -INFINITY;
        #pragma unroll
        for (int i = 0; i < 32; ++i) { mc = fmaxf(mc, c[i]); mb = fmaxf(mb, bc[i]); }
        #pragma unroll
        for (int o = 32; o > 0; o >>= 1) {
            mc = fmaxf(mc, __shfl_xor(mc, o, 64));
            mb = fmaxf(mb, __shfl_xor(mb, o, 64));
        }
        if (lane == 0) sm4[w] = mc;
        __syncthreads();
        mc = fmaxf(fmaxf(sm4[0], sm4[1]), fmaxf(sm4[2], sm4[3]));
        __syncthreads();
        if (lane == 0) sm4[w] = mb;
        __syncthreads();
        mb = fmaxf(fmaxf(sm4[0], sm4[1]), fmaxf(sm4[2], sm4[3]));
        __syncthreads();

        float zc = 0.f, zb = 0.f;
        #pragma unroll
        for (int i = 0; i < 32; ++i) { zc += __expf(c[i] - mc); zb += __expf(bc[i] - mb); }
        zc = wave_sum(zc); zb = wave_sum(zb);
        if (lane == 0) sm4[w] = zc;
        __syncthreads();
        zc = sm4[0] + sm4[1] + sm4[2] + sm4[3];
        __syncthreads();
        if (lane == 0) sm4[w] = zb;
        __syncthreads();
        zb = sm4[0] + sm4[1] + sm4[2] + sm4[3];
        __syncthreads();
        const float lnZc = __logf(zc);

        float te = 0.f, en = 0.f;
        #pragma unroll
        for (int i = 0; i < 32; ++i) {
            const float lsm = c[i] - mc - lnZc;
            te += __expf(c[i] - mc) * lsm;
            en += __expf(bc[i] - mb) * lsm;
        }
        te = wave_sum(te); en = wave_sum(en);
        if (lane == 0) sm4[w] = te;
        __syncthreads();
        te = sm4[0] + sm4[1] + sm4[2] + sm4[3];
        __syncthreads();
        if (lane == 0) sm4[w] = en;
        __syncthreads();
        en = sm4[0] + sm4[1] + sm4[2] + sm4[3];
        if (t == 0) {
            out[1] = en / zb;
            out[2] = te / zc;
        }
        return;
    }

    // ---- student role: rows 256..2047 ----
    __shared__ float smax[4];
    __shared__ float sred3[4][3];
    const int row = 256 + (bid - 3);
    const int v = row >> 8;             // 1..7
    const int b = row & 255;

    float y[32];
    const float* srow = student + (size_t)row * D;
    float m = -INFINITY;
    #pragma unroll
    for (int i = 0; i < 8; ++i) {
        float4 x = *(const float4*)(srow + i * 1024 + t * 4);
        y[i*4+0] = x.x * 10.f; y[i*4+1] = x.y * 10.f;
        y[i*4+2] = x.z * 10.f; y[i*4+3] = x.w * 10.f;
        m = fmaxf(m, fmaxf(fmaxf(y[i*4+0], y[i*4+1]), fmaxf(y[i*4+2], y[i*4+3])));
    }
    #pragma unroll
    for (int o = 32; o > 0; o >>= 1) m = fmaxf(m, __shfl_xor(m, o, 64));
    if (lane == 0) smax[w] = m;
    __syncthreads();
    const float M = fmaxf(fmaxf(smax[0], smax[1]), fmaxf(smax[2], smax[3]));

    float zs = 0.f;
    #pragma unroll
    for (int i = 0; i < 32; ++i) { y[i] = __expf(y[i] - M); zs += y[i]; }

    const float* g0 = g_ws + (size_t)b * D;
    const float* g1 = g_ws + (size_t)(256 + b) * D;
    float a0 = 0.f, a1 = 0.f;
    #pragma unroll
    for (int i = 0; i < 8; ++i) {
        float4 gg = *(const float4*)(g0 + i * 1024 + t * 4);
        a0 += y[i*4+0]*gg.x + y[i*4+1]*gg.y + y[i*4+2]*gg.z + y[i*4+3]*gg.w;
    }
    if (v >= 2) {
        #pragma unroll
        for (int i = 0; i < 8; ++i) {
            float4 gg = *(const float4*)(g1 + i * 1024 + t * 4);
            a1 += y[i*4+0]*gg.x + y[i*4+1]*gg.y + y[i*4+2]*gg.z + y[i*4+3]*gg.w;
        }
    }
    zs = wave_sum(zs); a0 = wave_sum(a0); a1 = wave_sum(a1);
    if (lane == 0) { sred3[w][0] = zs; sred3[w][1] = a0; sred3[w][2] = a1; }
    __syncthreads();
    if (t == 0) {
        const float Z  = sred3[0][0] + sred3[1][0] + sred3[2][0] + sred3[3][0];
        const float A0 = sred3[0][1] + sred3[1][1] + sred3[2][1] + sred3[3][1];
        const float A1 = sred3[0][2] + sred3[1][2] + sred3[2][2] + sred3[3][2];
        const float invZ = 1.0f / Z;
        float term = -10.f * A0 * invZ;
        if (v >= 2) term += -10.f * A1 * invZ;
        atomicAdd(out, term * (1.0f / 3328.0f));
    }
}

extern "C" void kernel_launch(void* const* d_in, const int* in_sizes, int n_in,
                              void* d_out, int out_size, void* d_ws, size_t ws_size,
                              hipStream_t stream) {
    const float* student = (const float*)d_in[0];
    const float* teacher = (const float*)d_in[1];
    const float* pred    = (const float*)d_in[2];
    const float* center  = (const float*)d_in[3];
    const int*   epoch   = (const int*)d_in[4];
    float* out = (float*)d_out;

    float* g_ws     = (float*)d_ws;                     // 512*8192 f (16 MB)
    float* part     = g_ws + (size_t)512 * D;           // 16*8192 f (512 KB)
    int*   idx_ws   = (int*)(part + (size_t)16 * D);    // 512*8 i
    float* p_ws     = (float*)(idx_ws + 512 * 8);       // 512*8 f
    float* part_lse = p_ws + 512 * 8;                   // 2048*8 f

    k_topk<<<512, NT, 0, stream>>>(teacher, center, epoch, idx_ws, p_ws, out);
    k_gather_colsum<<<2176, NT, 0, stream>>>(pred, idx_ws, p_ws, teacher,
                                             g_ws, part_lse, part);
    k_main<<<1795, NT, 0, stream>>>(student, g_ws, p_ws, part_lse, part, center, out);
}